// Round 1
// baseline (685.781 us; speedup 1.0000x reference)
//
#include <hip/hip_runtime.h>
#include <math.h>

#define B_N    64
#define H_N    512
#define V_N    32000
#define S_N    512
#define VEXT   32050
#define INF_F  1000000000000.0f

typedef __attribute__((ext_vector_type(4))) float floatx4;
typedef __attribute__((ext_vector_type(8))) __bf16 bf16x8;

// ---- output layout (floats) ----
#define OFF_OUT0 0
#define OFF_CTX  (B_N * VEXT)                 // 2051200
#define OFF_H1   (OFF_CTX + B_N * H_N)        // 2083968
#define OFF_C1   (OFF_H1 + B_N * H_N)         // 2116736
#define OFF_ATTN (OFF_C1 + B_N * H_N)         // 2149504

// ---- workspace layout (32-bit words) ----
#define WS_FLAG   0
#define WS_X      16
#define WS_GATES  (WS_X + B_N * H_N)                  // 32784
#define WS_Q      (WS_GATES + B_N * 4 * H_N)          // 163856
#define WS_KB     (WS_Q + B_N * H_N)                  // 196624
#define WS_EN     (WS_KB + B_N)                       // 196688
#define WS_COMB   (WS_EN + B_N * S_N)                 // 229456
#define WS_SEQE   (WS_COMB + B_N * H_N)               // 262224
#define WS_WSKBF  (WS_SEQE + B_N * S_N)               // 294992 (holds 512*512 ushort)
#define WS_LOGITS (WS_WSKBF + (H_N * H_N) / 2)        // 426064
#define WS_COPY   (WS_LOGITS + B_N * V_N)             // 2474064

__device__ __forceinline__ float sigm(float x) { return 1.0f / (1.0f + expf(-x)); }

__device__ __forceinline__ unsigned short f2bf(float f) {
    unsigned u = __float_as_uint(f);
    u += 0x7fffu + ((u >> 16) & 1u);   // round-to-nearest-even
    return (unsigned short)(u >> 16);
}

// order-preserving float<->uint encode for atomicMax-based scatter-max
__device__ __forceinline__ unsigned enc_f(float f) {
    unsigned u = __float_as_uint(f);
    return (u & 0x80000000u) ? ~u : (u | 0x80000000u);
}
__device__ __forceinline__ float dec_f(unsigned e) {
    unsigned u = (e & 0x80000000u) ? (e & 0x7fffffffu) : ~e;
    return __uint_as_float(u);
}

// ---------- detect bool-mask storage width (1 byte vs 4 byte) ----------
__global__ void kDetect(const unsigned int* __restrict__ m, int* __restrict__ flag) {
    __shared__ int any;
    if (threadIdx.x == 0) any = 0;
    __syncthreads();
    int loc = 0;
    // first 32768 bytes are valid under both layouts; byte-packed bools make words > 1
    for (int i = threadIdx.x; i < 8192; i += 256) loc |= (m[i] > 1u) ? 1 : 0;
    if (loc) any = 1;
    __syncthreads();
    if (threadIdx.x == 0) *flag = any;   // 1 => byte storage, 0 => int32 storage
}

// ---------- W_seqkey f32 -> bf16 (512KB, reused by all seq-GEMM blocks) ----------
__global__ void kConvertW(const float* __restrict__ W, unsigned short* __restrict__ wsk) {
    const int i = (blockIdx.x * 256 + threadIdx.x) * 4;
    float4 v = *(const float4*)(W + i);
    ushort4 h;
    h.x = f2bf(v.x); h.y = f2bf(v.y); h.z = f2bf(v.z); h.w = f2bf(v.w);
    *(ushort4*)(wsk + i) = h;
}

// ---------- init copy buffer to enc(-INF) ----------
__global__ void kFillCopy(unsigned int* __restrict__ copyenc) {
    const unsigned NE = enc_f(-INF_F);
    int i0 = (blockIdx.x * 256 + threadIdx.x) * 4;
#pragma unroll
    for (int k = 0; k < 4; k++) {
        int i = i0 + k;
        if (i < B_N * VEXT) copyenc[i] = NE;
    }
}

// ---------- x = [embed[id] | prev_context] @ W_reduce.T + b_reduce ----------
__global__ __launch_bounds__(256) void kEmbedReduce(
        const int* __restrict__ ids, const float* __restrict__ embed,
        const float* __restrict__ pctx, const float* __restrict__ Wred,
        const float* __restrict__ bred, float* __restrict__ x) {
    __shared__ float xc[1024];
    const int tid = threadIdx.x;
    const int b = blockIdx.x >> 1, half = blockIdx.x & 1;
    const float* er = embed + (size_t)ids[b] * 512;
    xc[tid] = er[tid];               xc[tid + 256] = er[tid + 256];
    xc[512 + tid] = pctx[b * 512 + tid]; xc[512 + tid + 256] = pctx[b * 512 + tid + 256];
    __syncthreads();
    const int j = half * 256 + tid;
    const float4* w4 = (const float4*)(Wred + (size_t)j * 1024);
    const float4* x4 = (const float4*)xc;
    float acc = bred[j];
    for (int k = 0; k < 256; k++) {
        float4 w = w4[k], xv = x4[k];
        acc += w.x * xv.x + w.y * xv.y + w.z * xv.z + w.w * xv.w;
    }
    x[b * 512 + j] = acc;
}

// ---------- gates = x @ W_ih.T + h0 @ W_hh.T + b_ih + b_hh ----------
__global__ __launch_bounds__(256) void kGates(
        const float* __restrict__ x, const float* __restrict__ h0,
        const float* __restrict__ Wih, const float* __restrict__ Whh,
        const float* __restrict__ bih, const float* __restrict__ bhh,
        float* __restrict__ gates) {
    __shared__ float xl[512], hl[512];
    const int tid = threadIdx.x;
    const int b = blockIdx.x >> 3, part = blockIdx.x & 7;
    xl[tid] = x[b * 512 + tid];  xl[tid + 256] = x[b * 512 + tid + 256];
    hl[tid] = h0[b * 512 + tid]; hl[tid + 256] = h0[b * 512 + tid + 256];
    __syncthreads();
    const int j = part * 256 + tid;
    const float4* wi4 = (const float4*)(Wih + (size_t)j * 512);
    const float4* wh4 = (const float4*)(Whh + (size_t)j * 512);
    const float4* x4 = (const float4*)xl;
    const float4* h4 = (const float4*)hl;
    float acc = bih[j] + bhh[j];
    for (int k = 0; k < 128; k++) {
        float4 w = wi4[k], xv = x4[k];
        acc += w.x * xv.x + w.y * xv.y + w.z * xv.z + w.w * xv.w;
    }
    for (int k = 0; k < 128; k++) {
        float4 w = wh4[k], hv = h4[k];
        acc += w.x * hv.x + w.y * hv.y + w.z * hv.z + w.w * hv.w;
    }
    gates[(size_t)b * 2048 + j] = acc;
}

// ---------- LSTM elementwise (PyTorch i,f,g,o order) ----------
__global__ __launch_bounds__(256) void kLstm(
        const float* __restrict__ gates, const float* __restrict__ c0,
        float* __restrict__ h1o, float* __restrict__ c1o) {
    const int idx = blockIdx.x * 256 + threadIdx.x;  // < 32768
    const int b = idx >> 9, j = idx & 511;
    const float gi = gates[(size_t)b * 2048 + j];
    const float gf = gates[(size_t)b * 2048 + 512 + j];
    const float gg = gates[(size_t)b * 2048 + 1024 + j];
    const float go = gates[(size_t)b * 2048 + 1536 + j];
    const float cp = c0[idx];
    const float c1 = sigm(gf) * cp + sigm(gi) * tanhf(gg);
    const float h1 = sigm(go) * tanhf(c1);
    h1o[idx] = h1;
    c1o[idx] = c1;
}

// ---------- q[b,k] = sum_h h1[b,h]*W_key[h,k]; kb[b] = b_key . h1[b] ----------
__global__ __launch_bounds__(256) void kQ(
        const float* __restrict__ h1, const float* __restrict__ Wkey,
        const float* __restrict__ bkey, float* __restrict__ q, float* __restrict__ kb) {
    __shared__ float hl[512];
    __shared__ float rd[256];
    const int tid = threadIdx.x;
    const int b = blockIdx.x >> 1, half = blockIdx.x & 1;
    hl[tid] = h1[b * 512 + tid]; hl[tid + 256] = h1[b * 512 + tid + 256];
    __syncthreads();
    const int k = half * 256 + tid;
    float acc = 0.f;
#pragma unroll 4
    for (int h = 0; h < 512; h++) acc += hl[h] * Wkey[(size_t)h * 512 + k];
    q[b * 512 + k] = acc;
    if (half == 0) {   // block-uniform branch
        float p = bkey[tid] * hl[tid] + bkey[tid + 256] * hl[tid + 256];
        rd[tid] = p; __syncthreads();
        for (int st = 128; st > 0; st >>= 1) {
            if (tid < st) rd[tid] += rd[tid + st];
            __syncthreads();
        }
        if (tid == 0) kb[b] = rd[0];
    }
}

// ---------- energies[b,s] = enc[b,s,:].q[b] + kb[b]; mask rows summing to 0 ----------
__global__ __launch_bounds__(256) void kEnergies(
        const float* __restrict__ enc, const float* __restrict__ q,
        const float* __restrict__ kb, float* __restrict__ energ) {
    __shared__ float ql[512];
    __shared__ float pe[256], ps[256];
    const int tid = threadIdx.x;
    const int b = blockIdx.x >> 2;
    const int sc = (blockIdx.x & 3) * 128;
    ql[tid] = q[b * 512 + tid]; ql[tid + 256] = q[b * 512 + tid + 256];
    __syncthreads();
    const int r = tid & 127, hi = tid >> 7;
    const float4* row4 = (const float4*)(enc + (size_t)(b * 512 + sc + r) * 512 + hi * 256);
    const float4* q4 = (const float4*)(ql + hi * 256);
    float e = 0.f, ssum = 0.f;
#pragma unroll 4
    for (int k = 0; k < 64; k++) {
        float4 ev = row4[k], qv = q4[k];
        e += ev.x * qv.x + ev.y * qv.y + ev.z * qv.z + ev.w * qv.w;
        ssum += ev.x + ev.y + ev.z + ev.w;
    }
    pe[tid] = e; ps[tid] = ssum;
    __syncthreads();
    if (tid < 128) {
        float ee = pe[tid] + pe[tid + 128] + kb[b];
        float sm = ps[tid] + ps[tid + 128];
        if (sm == 0.0f) ee = 1e-12f;        // enc_mask semantics
        energ[b * 512 + sc + tid] = ee;
    }
}

// ---------- softmax over S per b ----------
__global__ __launch_bounds__(256) void kSoftmax(
        const float* __restrict__ energ, float* __restrict__ attn) {
    __shared__ float el[512];
    __shared__ float rd[256];
    const int tid = threadIdx.x, b = blockIdx.x;
    el[tid] = energ[b * 512 + tid]; el[tid + 256] = energ[b * 512 + tid + 256];
    __syncthreads();
    rd[tid] = fmaxf(el[tid], el[tid + 256]); __syncthreads();
    for (int st = 128; st > 0; st >>= 1) {
        if (tid < st) rd[tid] = fmaxf(rd[tid], rd[tid + st]);
        __syncthreads();
    }
    const float m = rd[0]; __syncthreads();
    float v0 = expf(el[tid] - m), v1 = expf(el[tid + 256] - m);
    rd[tid] = v0 + v1; __syncthreads();
    for (int st = 128; st > 0; st >>= 1) {
        if (tid < st) rd[tid] += rd[tid + st];
        __syncthreads();
    }
    const float inv = 1.0f / rd[0];
    attn[b * 512 + tid] = v0 * inv;
    attn[b * 512 + tid + 256] = v1 * inv;
}

// ---------- context[b,h] = sum_s attn[b,s]*enc[b,s,h]  (atomicAdd partials) ----------
__global__ __launch_bounds__(256) void kContext(
        const float* __restrict__ enc, const float* __restrict__ attn,
        float* __restrict__ ctx) {
    __shared__ float al[64];
    const int tid = threadIdx.x;
    const int b = blockIdx.x >> 3, sc = (blockIdx.x & 7) * 64;
    if (tid < 64) al[tid] = attn[b * 512 + sc + tid];
    __syncthreads();
    float a0 = 0.f, a1 = 0.f;
    for (int s = 0; s < 64; s++) {
        const float* row = enc + (size_t)(b * 512 + sc + s) * 512;
        const float av = al[s];
        a0 += av * row[tid];
        a1 += av * row[tid + 256];
    }
    atomicAdd(&ctx[b * 512 + tid], a0);
    atomicAdd(&ctx[b * 512 + tid + 256], a1);
}

// ---------- combined = tanh([h1|ctx] @ W_comb.T + b_comb) ----------
__global__ __launch_bounds__(256) void kCombined(
        const float* __restrict__ h1, const float* __restrict__ ctx,
        const float* __restrict__ Wcomb, const float* __restrict__ bcomb,
        float* __restrict__ comb) {
    __shared__ float hc[1024];
    const int tid = threadIdx.x;
    const int b = blockIdx.x >> 1, half = blockIdx.x & 1;
    hc[tid] = h1[b * 512 + tid];        hc[tid + 256] = h1[b * 512 + tid + 256];
    hc[512 + tid] = ctx[b * 512 + tid]; hc[512 + tid + 256] = ctx[b * 512 + tid + 256];
    __syncthreads();
    const int j = half * 256 + tid;
    const float4* w4 = (const float4*)(Wcomb + (size_t)j * 1024);
    const float4* x4 = (const float4*)hc;
    float acc = bcomb[j];
    for (int k = 0; k < 256; k++) {
        float4 w = w4[k], xv = x4[k];
        acc += w.x * xv.x + w.y * xv.y + w.z * xv.z + w.w * xv.w;
    }
    comb[b * 512 + j] = tanhf(acc);
}

// ---------- logits[b,v] = combined[b] . W_out[v] + b_out[v]  (f32, k-split x4) ----------
__global__ __launch_bounds__(256) void kLogits(
        const float* __restrict__ comb, const float* __restrict__ Wout,
        const float* __restrict__ bout, float* __restrict__ logits) {
    __shared__ float cl[4][32][64];   // [kq][kk][b] also reused as reduction scratch
    const int tid = threadIdx.x;
    const int vt = tid & 63, kq = tid >> 6;
    const int v = blockIdx.x * 64 + vt;
    float acc[64];
#pragma unroll
    for (int i = 0; i < 64; i++) acc[i] = 0.f;
    for (int kc = 0; kc < 4; kc++) {
        __syncthreads();
        {   // stage comb chunk: thread (kq, vt=b) loads 32 consecutive floats
            const float4* s4 = (const float4*)(comb + (size_t)vt * 512 + kq * 128 + kc * 32);
#pragma unroll
            for (int qq = 0; qq < 8; qq++) {
                float4 vv = s4[qq];
                cl[kq][qq * 4 + 0][vt] = vv.x; cl[kq][qq * 4 + 1][vt] = vv.y;
                cl[kq][qq * 4 + 2][vt] = vv.z; cl[kq][qq * 4 + 3][vt] = vv.w;
            }
        }
        __syncthreads();
        float wreg[32];
        const float4* w4 = (const float4*)(Wout + (size_t)v * 512 + kq * 128 + kc * 32);
#pragma unroll
        for (int qq = 0; qq < 8; qq++) {
            float4 wv = w4[qq];
            wreg[qq * 4 + 0] = wv.x; wreg[qq * 4 + 1] = wv.y;
            wreg[qq * 4 + 2] = wv.z; wreg[qq * 4 + 3] = wv.w;
        }
#pragma unroll
        for (int kk = 0; kk < 32; kk++) {
            const float wv = wreg[kk];
            const float4* cp = (const float4*)&cl[kq][kk][0];   // wave-uniform -> broadcast
#pragma unroll
            for (int b4 = 0; b4 < 16; b4++) {
                float4 c4 = cp[b4];
                acc[b4 * 4 + 0] += wv * c4.x; acc[b4 * 4 + 1] += wv * c4.y;
                acc[b4 * 4 + 2] += wv * c4.z; acc[b4 * 4 + 3] += wv * c4.w;
            }
        }
    }
    float* red = &cl[0][0][0];
    __syncthreads();
    if (kq >= 2) {
#pragma unroll
        for (int b = 0; b < 64; b++) red[(kq - 2) * 4096 + vt * 64 + b] = acc[b];
    }
    __syncthreads();
    if (kq < 2) {
#pragma unroll
        for (int b = 0; b < 64; b++) acc[b] += red[kq * 4096 + vt * 64 + b];
    }
    __syncthreads();
    if (kq == 1) {
#pragma unroll
        for (int b = 0; b < 64; b++) red[vt * 64 + b] = acc[b];
    }
    __syncthreads();
    if (kq == 0) {
        const float bo = bout[v];
#pragma unroll
        for (int b = 0; b < 64; b++)
            logits[(size_t)b * 32000 + v] = acc[b] + red[vt * 64 + b] + bo;
    }
}

// ---------- seq_e[m] = sum_h tanh( (seqs @ W_seqkey.T)[m,h] ) * h1[b,h]  (bf16 MFMA) ----
// M=32768 rows, N=512, K=512. Block: 64 rows, full N. 8 waves: wave w covers n in
// [w*64, w*64+64) for all 4 m-subtiles -> 4x4 MFMA tiles, 64 acc VGPRs.
__global__ __launch_bounds__(512) void kSeqGemm(
        const float* __restrict__ seqs, const unsigned short* __restrict__ wsk,
        const float* __restrict__ h1g, float* __restrict__ seq_e) {
    __shared__ unsigned short a_lds[64 * 40];    // 64 rows x 32 k bf16, stride 40 (pad)
    __shared__ unsigned short b_lds[512 * 40];   // 512 n x 32 k bf16, stride 40 (pad)
    __shared__ float h1l[512];
    __shared__ float partf[8][64];
    const int tid = threadIdx.x;
    const int m0 = blockIdx.x * 64;
    const int b = m0 >> 9;                       // 512 rows per batch; 64 | 512 -> single b
    const int w = tid >> 6;
    const int lane = tid & 63;
    const int quad = lane >> 4;
    const int c16 = lane & 15;

    h1l[tid] = h1g[b * 512 + tid];

    floatx4 acc[4][4];
    const floatx4 zf = {0.f, 0.f, 0.f, 0.f};
#pragma unroll
    for (int i = 0; i < 4; i++)
#pragma unroll
        for (int j = 0; j < 4; j++) acc[i][j] = zf;

    const int arow = tid >> 3, aseg = tid & 7;
    for (int kc = 0; kc < 16; kc++) {
        const int k0 = kc * 32;
        __syncthreads();
        {   // stage A: 64x32 f32 -> bf16
            const float4 v = *(const float4*)(seqs + (size_t)(m0 + arow) * 512 + k0 + aseg * 4);
            ushort4 hv;
            hv.x = f2bf(v.x); hv.y = f2bf(v.y); hv.z = f2bf(v.z); hv.w = f2bf(v.w);
            *(ushort4*)&a_lds[arow * 40 + aseg * 4] = hv;
        }
        {   // stage B: 512x32 bf16 from pre-converted W_seqkey (L2-resident)
            const uint4* sp = (const uint4*)(wsk + (size_t)tid * 512 + k0);
            uint4* dp = (uint4*)&b_lds[tid * 40];
            dp[0] = sp[0]; dp[1] = sp[1]; dp[2] = sp[2]; dp[3] = sp[3];
        }
        __syncthreads();
        bf16x8 af[4], bfr[4];
#pragma unroll
        for (int ms = 0; ms < 4; ms++)
            af[ms] = *(const bf16x8*)&a_lds[(ms * 16 + c16) * 40 + quad * 8];
#pragma unroll
        for (int nt = 0; nt < 4; nt++)
            bfr[nt] = *(const bf16x8*)&b_lds[(w * 64 + nt * 16 + c16) * 40 + quad * 8];
#pragma unroll
        for (int ms = 0; ms < 4; ms++)
#pragma unroll
            for (int nt = 0; nt < 4; nt++)
                acc[ms][nt] = __builtin_amdgcn_mfma_f32_16x16x32_bf16(
                    af[ms], bfr[nt], acc[ms][nt], 0, 0, 0);
    }
    // epilogue: seq_e[m] = sum_n tanh(K[m,n]) * h1[b,n]
    float psum[16];
#pragma unroll
    for (int i = 0; i < 16; i++) psum[i] = 0.f;
#pragma unroll
    for (int ms = 0; ms < 4; ms++)
#pragma unroll
        for (int nt = 0; nt < 4; nt++) {
            const float hv = h1l[w * 64 + nt * 16 + c16];
#pragma unroll
            for (int r = 0; r < 4; r++)
                psum[ms * 4 + r] += tanhf(acc[ms][nt][r]) * hv;   // D: row=quad*4+r, col=c16
        }
#pragma unroll
    for (int d = 1; d < 16; d <<= 1)
#pragma unroll
        for (int i = 0; i < 16; i++) psum[i] += __shfl_xor(psum[i], d);
    if (c16 == 0) {
#pragma unroll
        for (int ms = 0; ms < 4; ms++)
#pragma unroll
            for (int r = 0; r < 4; r++)
                partf[w][ms * 16 + quad * 4 + r] = psum[ms * 4 + r];
    }
    __syncthreads();
    if (tid < 64) {
        float s = 0.f;
#pragma unroll
        for (int ww = 0; ww < 8; ww++) s += partf[ww][tid];
        seq_e[m0 + tid] = s;
    }
}

// ---------- scatter-max into extended-vocab copy buffer ----------
__global__ __launch_bounds__(512) void kScatter(
        const float* __restrict__ seq_e, const void* __restrict__ mask,
        const int* __restrict__ extix, const int* __restrict__ flag,
        unsigned int* __restrict__ copyenc) {
    const int tid = threadIdx.x, b = blockIdx.x;
    float e = seq_e[b * 512 + tid];
    bool mk;
    if (*flag) mk = ((const unsigned char*)mask)[b * 512 + tid] != 0;
    else       mk = ((const int*)mask)[b * 512 + tid] != 0;
    if (mk) e = 1e-12f;
    const int idx = extix[b * 512 + tid];
    atomicMax(&copyenc[(size_t)b * VEXT + idx], enc_f(e));
}

// ---------- assemble extended logits + copy, log_softmax over 32050 ----------
__global__ __launch_bounds__(256) void kFinal(
        const float* __restrict__ logits, const unsigned int* __restrict__ copyenc,
        float* __restrict__ out0) {
    __shared__ float rd[256];
    const int tid = threadIdx.x, b = blockIdx.x;
    const float* lrow = logits + (size_t)b * 32000;
    const unsigned int* crow = copyenc + (size_t)b * VEXT;
    float* orow = out0 + (size_t)b * VEXT;
    float lm = -3.0e38f;
    for (int j = tid; j < VEXT; j += 256) {
        float ext = (j < 32000) ? lrow[j] : 0.0f;
        float cv = dec_f(crow[j]);
        if (cv == -INF_F) cv = 0.0f;
        float o = ext + cv;
        if (o == 0.0f) o = -INF_F;
        orow[j] = o;
        lm = fmaxf(lm, o);
    }
    rd[tid] = lm; __syncthreads();
    for (int st = 128; st > 0; st >>= 1) {
        if (tid < st) rd[tid] = fmaxf(rd[tid], rd[tid + st]);
        __syncthreads();
    }
    const float m = rd[0]; __syncthreads();
    float ls = 0.f;
    for (int j = tid; j < VEXT; j += 256) ls += expf(orow[j] - m);
    rd[tid] = ls; __syncthreads();
    for (int st = 128; st > 0; st >>= 1) {
        if (tid < st) rd[tid] += rd[tid + st];
        __syncthreads();
    }
    const float lse = m + logf(rd[0]);
    __syncthreads();
    for (int j = tid; j < VEXT; j += 256) orow[j] -= lse;
}

extern "C" void kernel_launch(void* const* d_in, const int* in_sizes, int n_in,
                              void* d_out, int out_size, void* d_ws, size_t ws_size,
                              hipStream_t stream) {
    const int*   ids   = (const int*)d_in[0];
    const float* pctx  = (const float*)d_in[1];
    const float* h0    = (const float*)d_in[2];
    const float* c0    = (const float*)d_in[3];
    const float* enc   = (const float*)d_in[4];
    const float* seqs  = (const float*)d_in[5];
    const void*  mask  = d_in[6];
    const int*   extix = (const int*)d_in[7];
    const float* embed = (const float*)d_in[8];
    const float* Wred  = (const float*)d_in[9];
    const float* bred  = (const float*)d_in[10];
    const float* Wkey  = (const float*)d_in[11];
    const float* bkey  = (const float*)d_in[12];
    const float* Wcomb = (const float*)d_in[13];
    const float* bcomb = (const float*)d_in[14];
    const float* Wseqk = (const float*)d_in[15];
    const float* Wih   = (const float*)d_in[16];
    const float* Whh   = (const float*)d_in[17];
    const float* bih   = (const float*)d_in[18];
    const float* bhh   = (const float*)d_in[19];
    const float* Wout  = (const float*)d_in[20];
    const float* bout  = (const float*)d_in[21];
    (void)in_sizes; (void)n_in; (void)out_size; (void)ws_size;

    float* out = (float*)d_out;
    float* ws = (float*)d_ws;
    int* flag = (int*)ws;
    float* xws = ws + WS_X;
    float* gatesws = ws + WS_GATES;
    float* qws = ws + WS_Q;
    float* kbws = ws + WS_KB;
    float* enws = ws + WS_EN;
    float* combws = ws + WS_COMB;
    float* seqews = ws + WS_SEQE;
    unsigned short* wsk = (unsigned short*)(ws + WS_WSKBF);
    float* logitsws = ws + WS_LOGITS;
    unsigned int* copyenc = (unsigned int*)(ws + WS_COPY);

    kDetect<<<1, 256, 0, stream>>>((const unsigned int*)mask, flag);
    kConvertW<<<256, 256, 0, stream>>>(Wseqk, wsk);
    kFillCopy<<<2004, 256, 0, stream>>>(copyenc);
    kEmbedReduce<<<128, 256, 0, stream>>>(ids, embed, pctx, Wred, bred, xws);
    kGates<<<512, 256, 0, stream>>>(xws, h0, Wih, Whh, bih, bhh, gatesws);
    kLstm<<<128, 256, 0, stream>>>(gatesws, c0, out + OFF_H1, out + OFF_C1);
    kQ<<<128, 256, 0, stream>>>(out + OFF_H1, Wkey, bkey, qws, kbws);
    kEnergies<<<256, 256, 0, stream>>>(enc, qws, kbws, enws);
    kSoftmax<<<64, 256, 0, stream>>>(enws, out + OFF_ATTN);
    hipMemsetAsync(out + OFF_CTX, 0, (size_t)B_N * H_N * sizeof(float), stream);
    kContext<<<512, 256, 0, stream>>>(enc, out + OFF_ATTN, out + OFF_CTX);
    kCombined<<<128, 256, 0, stream>>>(out + OFF_H1, out + OFF_CTX, Wcomb, bcomb, combws);
    kLogits<<<500, 256, 0, stream>>>(combws, Wout, bout, logitsws);
    kSeqGemm<<<512, 512, 0, stream>>>(seqs, wsk, out + OFF_H1, seqews);
    kScatter<<<64, 512, 0, stream>>>(seqews, mask, extix, flag, copyenc);
    kFinal<<<64, 256, 0, stream>>>(logitsws, copyenc, out + OFF_OUT0);
}

// Round 2
// 607.225 us; speedup vs baseline: 1.1294x; 1.1294x over previous
//
#include <hip/hip_runtime.h>
#include <math.h>

#define B_N    64
#define H_N    512
#define V_N    32000
#define S_N    512
#define VEXT   32050
#define INF_F  1000000000000.0f

typedef __attribute__((ext_vector_type(4))) float floatx4;
typedef __attribute__((ext_vector_type(8))) __bf16 bf16x8;

// ---- output layout (floats) ----
#define OFF_OUT0 0
#define OFF_CTX  (B_N * VEXT)                 // 2051200
#define OFF_H1   (OFF_CTX + B_N * H_N)        // 2083968
#define OFF_C1   (OFF_H1 + B_N * H_N)        // 2116736
#define OFF_ATTN (OFF_C1 + B_N * H_N)        // 2149504

// ---- workspace layout (32-bit words) ----
#define WS_FLAG   0
#define WS_X      16
#define WS_GATES  (WS_X + B_N * H_N)                  // 32784
#define WS_Q      (WS_GATES + B_N * 4 * H_N)          // 163856
#define WS_KB     (WS_Q + B_N * H_N)                  // 196624
#define WS_EN     (WS_KB + B_N)                       // 196688
#define WS_COMB   (WS_EN + B_N * S_N)                 // 229456
#define WS_SEQE   (WS_COMB + B_N * H_N)               // 262224
#define WS_WSKBF  (WS_SEQE + B_N * S_N)               // 294992 (holds 512*512 ushort)
#define WS_LOGITS (WS_WSKBF + (H_N * H_N) / 2)        // 426064
#define WS_COPY   (WS_LOGITS + B_N * V_N)             // 2474064
#define WS_RMAX   (WS_COPY + B_N * VEXT)              // 4525264 (64 uints)
#define WS_RSUM   (WS_RMAX + B_N)                     // +64 floats

__device__ __forceinline__ float sigm(float x) { return 1.0f / (1.0f + expf(-x)); }

__device__ __forceinline__ unsigned short f2bf(float f) {
    unsigned u = __float_as_uint(f);
    u += 0x7fffu + ((u >> 16) & 1u);   // round-to-nearest-even
    return (unsigned short)(u >> 16);
}

// order-preserving float<->uint encode for atomicMax-based scatter-max
__device__ __forceinline__ unsigned enc_f(float f) {
    unsigned u = __float_as_uint(f);
    return (u & 0x80000000u) ? ~u : (u | 0x80000000u);
}
__device__ __forceinline__ float dec_f(unsigned e) {
    unsigned u = (e & 0x80000000u) ? (e & 0x7fffffffu) : ~e;
    return __uint_as_float(u);
}

// ---------- detect bool-mask storage width (1 byte vs 4 byte) ----------
__global__ void kDetect(const unsigned int* __restrict__ m, int* __restrict__ flag) {
    __shared__ int any;
    if (threadIdx.x == 0) any = 0;
    __syncthreads();
    int loc = 0;
    // first 32768 bytes are valid under both layouts; byte-packed bools make words > 1
    for (int i = threadIdx.x; i < 8192; i += 256) loc |= (m[i] > 1u) ? 1 : 0;
    if (loc) any = 1;
    __syncthreads();
    if (threadIdx.x == 0) *flag = any;   // 1 => byte storage, 0 => int32 storage
}

// ---------- W_seqkey f32 -> bf16 (512KB, reused by all seq-GEMM blocks) ----------
__global__ void kConvertW(const float* __restrict__ W, unsigned short* __restrict__ wsk) {
    const int i = (blockIdx.x * 256 + threadIdx.x) * 4;
    float4 v = *(const float4*)(W + i);
    ushort4 h;
    h.x = f2bf(v.x); h.y = f2bf(v.y); h.z = f2bf(v.z); h.w = f2bf(v.w);
    *(ushort4*)(wsk + i) = h;
}

// ---------- init copy buffer to enc(-INF); block 0 also inits row max/sum ----------
__global__ void kFillCopy(unsigned int* __restrict__ copyenc,
                          unsigned int* __restrict__ rmax, float* __restrict__ rsum) {
    const unsigned NE = enc_f(-INF_F);
    if (blockIdx.x == 0 && threadIdx.x < B_N) {
        rmax[threadIdx.x] = 0u;       // below enc of any real float
        rsum[threadIdx.x] = 0.0f;
    }
    int i0 = (blockIdx.x * 256 + threadIdx.x) * 4;
#pragma unroll
    for (int k = 0; k < 4; k++) {
        int i = i0 + k;
        if (i < B_N * VEXT) copyenc[i] = NE;
    }
}

// ---------- x = [embed[id] | prev_context] @ W_reduce.T + b_reduce ----------
__global__ __launch_bounds__(256) void kEmbedReduce(
        const int* __restrict__ ids, const float* __restrict__ embed,
        const float* __restrict__ pctx, const float* __restrict__ Wred,
        const float* __restrict__ bred, float* __restrict__ x) {
    __shared__ float xc[1024];
    const int tid = threadIdx.x;
    const int b = blockIdx.x >> 1, half = blockIdx.x & 1;
    const float* er = embed + (size_t)ids[b] * 512;
    xc[tid] = er[tid];               xc[tid + 256] = er[tid + 256];
    xc[512 + tid] = pctx[b * 512 + tid]; xc[512 + tid + 256] = pctx[b * 512 + tid + 256];
    __syncthreads();
    const int j = half * 256 + tid;
    const float4* w4 = (const float4*)(Wred + (size_t)j * 1024);
    const float4* x4 = (const float4*)xc;
    float acc = bred[j];
    for (int k = 0; k < 256; k++) {
        float4 w = w4[k], xv = x4[k];
        acc += w.x * xv.x + w.y * xv.y + w.z * xv.z + w.w * xv.w;
    }
    x[b * 512 + j] = acc;
}

// ---------- gates = x @ W_ih.T + h0 @ W_hh.T + b_ih + b_hh ----------
__global__ __launch_bounds__(256) void kGates(
        const float* __restrict__ x, const float* __restrict__ h0,
        const float* __restrict__ Wih, const float* __restrict__ Whh,
        const float* __restrict__ bih, const float* __restrict__ bhh,
        float* __restrict__ gates) {
    __shared__ float xl[512], hl[512];
    const int tid = threadIdx.x;
    const int b = blockIdx.x >> 3, part = blockIdx.x & 7;
    xl[tid] = x[b * 512 + tid];  xl[tid + 256] = x[b * 512 + tid + 256];
    hl[tid] = h0[b * 512 + tid]; hl[tid + 256] = h0[b * 512 + tid + 256];
    __syncthreads();
    const int j = part * 256 + tid;
    const float4* wi4 = (const float4*)(Wih + (size_t)j * 512);
    const float4* wh4 = (const float4*)(Whh + (size_t)j * 512);
    const float4* x4 = (const float4*)xl;
    const float4* h4 = (const float4*)hl;
    float acc = bih[j] + bhh[j];
    for (int k = 0; k < 128; k++) {
        float4 w = wi4[k], xv = x4[k];
        acc += w.x * xv.x + w.y * xv.y + w.z * xv.z + w.w * xv.w;
    }
    for (int k = 0; k < 128; k++) {
        float4 w = wh4[k], hv = h4[k];
        acc += w.x * hv.x + w.y * hv.y + w.z * hv.z + w.w * hv.w;
    }
    gates[(size_t)b * 2048 + j] = acc;
}

// ---------- LSTM elementwise (PyTorch i,f,g,o order) ----------
__global__ __launch_bounds__(256) void kLstm(
        const float* __restrict__ gates, const float* __restrict__ c0,
        float* __restrict__ h1o, float* __restrict__ c1o) {
    const int idx = blockIdx.x * 256 + threadIdx.x;  // < 32768
    const int b = idx >> 9, j = idx & 511;
    const float gi = gates[(size_t)b * 2048 + j];
    const float gf = gates[(size_t)b * 2048 + 512 + j];
    const float gg = gates[(size_t)b * 2048 + 1024 + j];
    const float go = gates[(size_t)b * 2048 + 1536 + j];
    const float cp = c0[idx];
    const float c1 = sigm(gf) * cp + sigm(gi) * tanhf(gg);
    const float h1 = sigm(go) * tanhf(c1);
    h1o[idx] = h1;
    c1o[idx] = c1;
}

// ---------- q[b,k] = sum_h h1[b,h]*W_key[h,k]; kb[b] = b_key . h1[b] ----------
__global__ __launch_bounds__(256) void kQ(
        const float* __restrict__ h1, const float* __restrict__ Wkey,
        const float* __restrict__ bkey, float* __restrict__ q, float* __restrict__ kb) {
    __shared__ float hl[512];
    __shared__ float rd[256];
    const int tid = threadIdx.x;
    const int b = blockIdx.x >> 1, half = blockIdx.x & 1;
    hl[tid] = h1[b * 512 + tid]; hl[tid + 256] = h1[b * 512 + tid + 256];
    __syncthreads();
    const int k = half * 256 + tid;
    float acc = 0.f;
#pragma unroll 4
    for (int h = 0; h < 512; h++) acc += hl[h] * Wkey[(size_t)h * 512 + k];
    q[b * 512 + k] = acc;
    if (half == 0) {   // block-uniform branch
        float p = bkey[tid] * hl[tid] + bkey[tid + 256] * hl[tid + 256];
        rd[tid] = p; __syncthreads();
        for (int st = 128; st > 0; st >>= 1) {
            if (tid < st) rd[tid] += rd[tid + st];
            __syncthreads();
        }
        if (tid == 0) kb[b] = rd[0];
    }
}

// ---------- energies[b,s] = enc[b,s,:].q[b] + kb[b]; mask rows summing to 0 ----------
__global__ __launch_bounds__(256) void kEnergies(
        const float* __restrict__ enc, const float* __restrict__ q,
        const float* __restrict__ kb, float* __restrict__ energ) {
    __shared__ float ql[512];
    __shared__ float pe[256], ps[256];
    const int tid = threadIdx.x;
    const int b = blockIdx.x >> 2;
    const int sc = (blockIdx.x & 3) * 128;
    ql[tid] = q[b * 512 + tid]; ql[tid + 256] = q[b * 512 + tid + 256];
    __syncthreads();
    const int r = tid & 127, hi = tid >> 7;
    const float4* row4 = (const float4*)(enc + (size_t)(b * 512 + sc + r) * 512 + hi * 256);
    const float4* q4 = (const float4*)(ql + hi * 256);
    float e = 0.f, ssum = 0.f;
#pragma unroll 4
    for (int k = 0; k < 64; k++) {
        float4 ev = row4[k], qv = q4[k];
        e += ev.x * qv.x + ev.y * qv.y + ev.z * qv.z + ev.w * qv.w;
        ssum += ev.x + ev.y + ev.z + ev.w;
    }
    pe[tid] = e; ps[tid] = ssum;
    __syncthreads();
    if (tid < 128) {
        float ee = pe[tid] + pe[tid + 128] + kb[b];
        float sm = ps[tid] + ps[tid + 128];
        if (sm == 0.0f) ee = 1e-12f;        // enc_mask semantics
        energ[b * 512 + sc + tid] = ee;
    }
}

// ---------- softmax over S per b ----------
__global__ __launch_bounds__(256) void kSoftmax(
        const float* __restrict__ energ, float* __restrict__ attn) {
    __shared__ float el[512];
    __shared__ float rd[256];
    const int tid = threadIdx.x, b = blockIdx.x;
    el[tid] = energ[b * 512 + tid]; el[tid + 256] = energ[b * 512 + tid + 256];
    __syncthreads();
    rd[tid] = fmaxf(el[tid], el[tid + 256]); __syncthreads();
    for (int st = 128; st > 0; st >>= 1) {
        if (tid < st) rd[tid] = fmaxf(rd[tid], rd[tid + st]);
        __syncthreads();
    }
    const float m = rd[0]; __syncthreads();
    float v0 = expf(el[tid] - m), v1 = expf(el[tid + 256] - m);
    rd[tid] = v0 + v1; __syncthreads();
    for (int st = 128; st > 0; st >>= 1) {
        if (tid < st) rd[tid] += rd[tid + st];
        __syncthreads();
    }
    const float inv = 1.0f / rd[0];
    attn[b * 512 + tid] = v0 * inv;
    attn[b * 512 + tid + 256] = v1 * inv;
}

// ---------- context[b,h] = sum_s attn[b,s]*enc[b,s,h]  (atomicAdd partials) ----------
__global__ __launch_bounds__(256) void kContext(
        const float* __restrict__ enc, const float* __restrict__ attn,
        float* __restrict__ ctx) {
    __shared__ float al[64];
    const int tid = threadIdx.x;
    const int b = blockIdx.x >> 3, sc = (blockIdx.x & 7) * 64;
    if (tid < 64) al[tid] = attn[b * 512 + sc + tid];
    __syncthreads();
    float a0 = 0.f, a1 = 0.f;
    for (int s = 0; s < 64; s++) {
        const float* row = enc + (size_t)(b * 512 + sc + s) * 512;
        const float av = al[s];
        a0 += av * row[tid];
        a1 += av * row[tid + 256];
    }
    atomicAdd(&ctx[b * 512 + tid], a0);
    atomicAdd(&ctx[b * 512 + tid + 256], a1);
}

// ---------- combined = tanh([h1|ctx] @ W_comb.T + b_comb) ----------
__global__ __launch_bounds__(256) void kCombined(
        const float* __restrict__ h1, const float* __restrict__ ctx,
        const float* __restrict__ Wcomb, const float* __restrict__ bcomb,
        float* __restrict__ comb) {
    __shared__ float hc[1024];
    const int tid = threadIdx.x;
    const int b = blockIdx.x >> 1, half = blockIdx.x & 1;
    hc[tid] = h1[b * 512 + tid];        hc[tid + 256] = h1[b * 512 + tid + 256];
    hc[512 + tid] = ctx[b * 512 + tid]; hc[512 + tid + 256] = ctx[b * 512 + tid + 256];
    __syncthreads();
    const int j = half * 256 + tid;
    const float4* w4 = (const float4*)(Wcomb + (size_t)j * 1024);
    const float4* x4 = (const float4*)hc;
    float acc = bcomb[j];
    for (int k = 0; k < 256; k++) {
        float4 w = w4[k], xv = x4[k];
        acc += w.x * xv.x + w.y * xv.y + w.z * xv.z + w.w * xv.w;
    }
    comb[b * 512 + j] = tanhf(acc);
}

// ---------- logits[b,v] = combined[b] . W_out[v] + b_out[v]  (f32, k-split x4) ----------
__global__ __launch_bounds__(256) void kLogits(
        const float* __restrict__ comb, const float* __restrict__ Wout,
        const float* __restrict__ bout, float* __restrict__ logits) {
    __shared__ float cl[4][32][64];   // [kq][kk][b] also reused as reduction scratch
    const int tid = threadIdx.x;
    const int vt = tid & 63, kq = tid >> 6;
    const int v = blockIdx.x * 64 + vt;
    float acc[64];
#pragma unroll
    for (int i = 0; i < 64; i++) acc[i] = 0.f;
    for (int kc = 0; kc < 4; kc++) {
        __syncthreads();
        {   // stage comb chunk: thread (kq, vt=b) loads 32 consecutive floats
            const float4* s4 = (const float4*)(comb + (size_t)vt * 512 + kq * 128 + kc * 32);
#pragma unroll
            for (int qq = 0; qq < 8; qq++) {
                float4 vv = s4[qq];
                cl[kq][qq * 4 + 0][vt] = vv.x; cl[kq][qq * 4 + 1][vt] = vv.y;
                cl[kq][qq * 4 + 2][vt] = vv.z; cl[kq][qq * 4 + 3][vt] = vv.w;
            }
        }
        __syncthreads();
        float wreg[32];
        const float4* w4 = (const float4*)(Wout + (size_t)v * 512 + kq * 128 + kc * 32);
#pragma unroll
        for (int qq = 0; qq < 8; qq++) {
            float4 wv = w4[qq];
            wreg[qq * 4 + 0] = wv.x; wreg[qq * 4 + 1] = wv.y;
            wreg[qq * 4 + 2] = wv.z; wreg[qq * 4 + 3] = wv.w;
        }
#pragma unroll
        for (int kk = 0; kk < 32; kk++) {
            const float wv = wreg[kk];
            const float4* cp = (const float4*)&cl[kq][kk][0];   // wave-uniform -> broadcast
#pragma unroll
            for (int b4 = 0; b4 < 16; b4++) {
                float4 c4 = cp[b4];
                acc[b4 * 4 + 0] += wv * c4.x; acc[b4 * 4 + 1] += wv * c4.y;
                acc[b4 * 4 + 2] += wv * c4.z; acc[b4 * 4 + 3] += wv * c4.w;
            }
        }
    }
    float* red = &cl[0][0][0];
    __syncthreads();
    if (kq >= 2) {
#pragma unroll
        for (int b = 0; b < 64; b++) red[(kq - 2) * 4096 + vt * 64 + b] = acc[b];
    }
    __syncthreads();
    if (kq < 2) {
#pragma unroll
        for (int b = 0; b < 64; b++) acc[b] += red[kq * 4096 + vt * 64 + b];
    }
    __syncthreads();
    if (kq == 1) {
#pragma unroll
        for (int b = 0; b < 64; b++) red[vt * 64 + b] = acc[b];
    }
    __syncthreads();
    if (kq == 0) {
        const float bo = bout[v];
#pragma unroll
        for (int b = 0; b < 64; b++)
            logits[(size_t)b * 32000 + v] = acc[b] + red[vt * 64 + b] + bo;
    }
}

// ---------- seq_e[m] = sum_h tanh( (seqs @ W_seqkey.T)[m,h] ) * h1[b,h]  (bf16 MFMA) ----
__global__ __launch_bounds__(512) void kSeqGemm(
        const float* __restrict__ seqs, const unsigned short* __restrict__ wsk,
        const float* __restrict__ h1g, float* __restrict__ seq_e) {
    __shared__ unsigned short a_lds[64 * 40];    // 64 rows x 32 k bf16, stride 40 (pad)
    __shared__ unsigned short b_lds[512 * 40];   // 512 n x 32 k bf16, stride 40 (pad)
    __shared__ float h1l[512];
    __shared__ float partf[8][64];
    const int tid = threadIdx.x;
    const int m0 = blockIdx.x * 64;
    const int b = m0 >> 9;                       // 512 rows per batch; 64 | 512 -> single b
    const int w = tid >> 6;
    const int lane = tid & 63;
    const int quad = lane >> 4;
    const int c16 = lane & 15;

    h1l[tid] = h1g[b * 512 + tid];

    floatx4 acc[4][4];
    const floatx4 zf = {0.f, 0.f, 0.f, 0.f};
#pragma unroll
    for (int i = 0; i < 4; i++)
#pragma unroll
        for (int j = 0; j < 4; j++) acc[i][j] = zf;

    const int arow = tid >> 3, aseg = tid & 7;
    for (int kc = 0; kc < 16; kc++) {
        const int k0 = kc * 32;
        __syncthreads();
        {   // stage A: 64x32 f32 -> bf16
            const float4 v = *(const float4*)(seqs + (size_t)(m0 + arow) * 512 + k0 + aseg * 4);
            ushort4 hv;
            hv.x = f2bf(v.x); hv.y = f2bf(v.y); hv.z = f2bf(v.z); hv.w = f2bf(v.w);
            *(ushort4*)&a_lds[arow * 40 + aseg * 4] = hv;
        }
        {   // stage B: 512x32 bf16 from pre-converted W_seqkey (L2-resident)
            const uint4* sp = (const uint4*)(wsk + (size_t)tid * 512 + k0);
            uint4* dp = (uint4*)&b_lds[tid * 40];
            dp[0] = sp[0]; dp[1] = sp[1]; dp[2] = sp[2]; dp[3] = sp[3];
        }
        __syncthreads();
        bf16x8 af[4], bfr[4];
#pragma unroll
        for (int ms = 0; ms < 4; ms++)
            af[ms] = *(const bf16x8*)&a_lds[(ms * 16 + c16) * 40 + quad * 8];
#pragma unroll
        for (int nt = 0; nt < 4; nt++)
            bfr[nt] = *(const bf16x8*)&b_lds[(w * 64 + nt * 16 + c16) * 40 + quad * 8];
#pragma unroll
        for (int ms = 0; ms < 4; ms++)
#pragma unroll
            for (int nt = 0; nt < 4; nt++)
                acc[ms][nt] = __builtin_amdgcn_mfma_f32_16x16x32_bf16(
                    af[ms], bfr[nt], acc[ms][nt], 0, 0, 0);
    }
    // epilogue: seq_e[m] = sum_n tanh(K[m,n]) * h1[b,n]
    float psum[16];
#pragma unroll
    for (int i = 0; i < 16; i++) psum[i] = 0.f;
#pragma unroll
    for (int ms = 0; ms < 4; ms++)
#pragma unroll
        for (int nt = 0; nt < 4; nt++) {
            const float hv = h1l[w * 64 + nt * 16 + c16];
#pragma unroll
            for (int r = 0; r < 4; r++)
                psum[ms * 4 + r] += tanhf(acc[ms][nt][r]) * hv;   // D: row=quad*4+r, col=c16
        }
#pragma unroll
    for (int d = 1; d < 16; d <<= 1)
#pragma unroll
        for (int i = 0; i < 16; i++) psum[i] += __shfl_xor(psum[i], d);
    if (c16 == 0) {
#pragma unroll
        for (int ms = 0; ms < 4; ms++)
#pragma unroll
            for (int r = 0; r < 4; r++)
                partf[w][ms * 16 + quad * 4 + r] = psum[ms * 4 + r];
    }
    __syncthreads();
    if (tid < 64) {
        float s = 0.f;
#pragma unroll
        for (int ww = 0; ww < 8; ww++) s += partf[ww][tid];
        seq_e[m0 + tid] = s;
    }
}

// ---------- scatter-max into extended-vocab copy buffer ----------
__global__ __launch_bounds__(512) void kScatter(
        const float* __restrict__ seq_e, const void* __restrict__ mask,
        const int* __restrict__ extix, const int* __restrict__ flag,
        unsigned int* __restrict__ copyenc) {
    const int tid = threadIdx.x, b = blockIdx.x;
    float e = seq_e[b * 512 + tid];
    bool mk;
    if (*flag) mk = ((const unsigned char*)mask)[b * 512 + tid] != 0;
    else       mk = ((const int*)mask)[b * 512 + tid] != 0;
    if (mk) e = 1e-12f;
    const int idx = extix[b * 512 + tid];
    atomicMax(&copyenc[(size_t)b * VEXT + idx], enc_f(e));
}

// ---------- log_softmax stage 1: assemble o, write, atomicMax row max ----------
__global__ __launch_bounds__(256) void kFinal1(
        const float* __restrict__ logits, const unsigned int* __restrict__ copyenc,
        float* __restrict__ out0, unsigned int* __restrict__ rmax) {
    __shared__ float rd[4];
    const int tid = threadIdx.x;
    const int b = blockIdx.x >> 4, chunk = blockIdx.x & 15;
    const int base = chunk * 2048 + tid;
    const float* lrow = logits + (size_t)b * 32000;
    const unsigned int* crow = copyenc + (size_t)b * VEXT;
    float* orow = out0 + (size_t)b * VEXT;
    float lm = -3.0e38f;
#pragma unroll
    for (int k = 0; k < 8; k++) {
        const int j = base + k * 256;
        if (j < VEXT) {
            float ext = (j < 32000) ? lrow[j] : 0.0f;
            float cv = dec_f(crow[j]);
            if (cv == -INF_F) cv = 0.0f;
            float o = ext + cv;
            if (o == 0.0f) o = -INF_F;
            orow[j] = o;
            lm = fmaxf(lm, o);
        }
    }
#pragma unroll
    for (int d = 1; d < 64; d <<= 1) lm = fmaxf(lm, __shfl_xor(lm, d));
    if ((tid & 63) == 0) rd[tid >> 6] = lm;
    __syncthreads();
    if (tid == 0) {
        float m = fmaxf(fmaxf(rd[0], rd[1]), fmaxf(rd[2], rd[3]));
        atomicMax(&rmax[b], enc_f(m));
    }
}

// ---------- log_softmax stage 2: partial exp-sums ----------
__global__ __launch_bounds__(256) void kFinal2(
        const float* __restrict__ out0, const unsigned int* __restrict__ rmax,
        float* __restrict__ rsum) {
    __shared__ float rd[4];
    const int tid = threadIdx.x;
    const int b = blockIdx.x >> 4, chunk = blockIdx.x & 15;
    const int base = chunk * 2048 + tid;
    const float* orow = out0 + (size_t)b * VEXT;
    const float m = dec_f(rmax[b]);
    float s = 0.f;
#pragma unroll
    for (int k = 0; k < 8; k++) {
        const int j = base + k * 256;
        if (j < VEXT) s += expf(orow[j] - m);
    }
#pragma unroll
    for (int d = 1; d < 64; d <<= 1) s += __shfl_xor(s, d);
    if ((tid & 63) == 0) rd[tid >> 6] = s;
    __syncthreads();
    if (tid == 0) atomicAdd(&rsum[b], rd[0] + rd[1] + rd[2] + rd[3]);
}

// ---------- log_softmax stage 3: subtract lse ----------
__global__ __launch_bounds__(256) void kFinal3(
        float* __restrict__ out0, const unsigned int* __restrict__ rmax,
        const float* __restrict__ rsum) {
    const int tid = threadIdx.x;
    const int b = blockIdx.x >> 4, chunk = blockIdx.x & 15;
    const int base = chunk * 2048 + tid;
    float* orow = out0 + (size_t)b * VEXT;
    const float lse = dec_f(rmax[b]) + logf(rsum[b]);
#pragma unroll
    for (int k = 0; k < 8; k++) {
        const int j = base + k * 256;
        if (j < VEXT) orow[j] -= lse;
    }
}

extern "C" void kernel_launch(void* const* d_in, const int* in_sizes, int n_in,
                              void* d_out, int out_size, void* d_ws, size_t ws_size,
                              hipStream_t stream) {
    const int*   ids   = (const int*)d_in[0];
    const float* pctx  = (const float*)d_in[1];
    const float* h0    = (const float*)d_in[2];
    const float* c0    = (const float*)d_in[3];
    const float* enc   = (const float*)d_in[4];
    const float* seqs  = (const float*)d_in[5];
    const void*  mask  = d_in[6];
    const int*   extix = (const int*)d_in[7];
    const float* embed = (const float*)d_in[8];
    const float* Wred  = (const float*)d_in[9];
    const float* bred  = (const float*)d_in[10];
    const float* Wkey  = (const float*)d_in[11];
    const float* bkey  = (const float*)d_in[12];
    const float* Wcomb = (const float*)d_in[13];
    const float* bcomb = (const float*)d_in[14];
    const float* Wseqk = (const float*)d_in[15];
    const float* Wih   = (const float*)d_in[16];
    const float* Whh   = (const float*)d_in[17];
    const float* bih   = (const float*)d_in[18];
    const float* bhh   = (const float*)d_in[19];
    const float* Wout  = (const float*)d_in[20];
    const float* bout  = (const float*)d_in[21];
    (void)in_sizes; (void)n_in; (void)out_size; (void)ws_size;

    float* out = (float*)d_out;
    float* ws = (float*)d_ws;
    int* flag = (int*)ws;
    float* xws = ws + WS_X;
    float* gatesws = ws + WS_GATES;
    float* qws = ws + WS_Q;
    float* kbws = ws + WS_KB;
    float* enws = ws + WS_EN;
    float* combws = ws + WS_COMB;
    float* seqews = ws + WS_SEQE;
    unsigned short* wsk = (unsigned short*)(ws + WS_WSKBF);
    float* logitsws = ws + WS_LOGITS;
    unsigned int* copyenc = (unsigned int*)(ws + WS_COPY);
    unsigned int* rmax = (unsigned int*)(ws + WS_RMAX);
    float* rsum = ws + WS_RSUM;

    kDetect<<<1, 256, 0, stream>>>((const unsigned int*)mask, flag);
    kConvertW<<<256, 256, 0, stream>>>(Wseqk, wsk);
    kFillCopy<<<2004, 256, 0, stream>>>(copyenc, rmax, rsum);
    kEmbedReduce<<<128, 256, 0, stream>>>(ids, embed, pctx, Wred, bred, xws);
    kGates<<<512, 256, 0, stream>>>(xws, h0, Wih, Whh, bih, bhh, gatesws);
    kLstm<<<128, 256, 0, stream>>>(gatesws, c0, out + OFF_H1, out + OFF_C1);
    kQ<<<128, 256, 0, stream>>>(out + OFF_H1, Wkey, bkey, qws, kbws);
    kEnergies<<<256, 256, 0, stream>>>(enc, qws, kbws, enws);
    kSoftmax<<<64, 256, 0, stream>>>(enws, out + OFF_ATTN);
    hipMemsetAsync(out + OFF_CTX, 0, (size_t)B_N * H_N * sizeof(float), stream);
    kContext<<<512, 256, 0, stream>>>(enc, out + OFF_ATTN, out + OFF_CTX);
    kCombined<<<128, 256, 0, stream>>>(out + OFF_H1, out + OFF_CTX, Wcomb, bcomb, combws);
    kLogits<<<500, 256, 0, stream>>>(combws, Wout, bout, logitsws);
    kSeqGemm<<<512, 512, 0, stream>>>(seqs, wsk, out + OFF_H1, seqews);
    kScatter<<<64, 512, 0, stream>>>(seqews, mask, extix, flag, copyenc);
    kFinal1<<<1024, 256, 0, stream>>>(logitsws, copyenc, out + OFF_OUT0, rmax);
    kFinal2<<<1024, 256, 0, stream>>>(out + OFF_OUT0, rmax, rsum);
    kFinal3<<<1024, 256, 0, stream>>>(out + OFF_OUT0, rmax, rsum);
}

// Round 3
// 571.695 us; speedup vs baseline: 1.1996x; 1.0621x over previous
//
#include <hip/hip_runtime.h>
#include <math.h>

#define B_N    64
#define H_N    512
#define V_N    32000
#define S_N    512
#define VEXT   32050
#define INF_F  1000000000000.0f

typedef __attribute__((ext_vector_type(4))) float floatx4;
typedef __attribute__((ext_vector_type(8))) __bf16 bf16x8;

// ---- output layout (floats) ----
#define OFF_OUT0 0
#define OFF_CTX  (B_N * VEXT)                 // 2051200
#define OFF_H1   (OFF_CTX + B_N * H_N)        // 2083968
#define OFF_C1   (OFF_H1 + B_N * H_N)        // 2116736
#define OFF_ATTN (OFF_C1 + B_N * H_N)        // 2149504

// ---- workspace layout (32-bit words) ----
#define WS_FLAG   0
#define WS_X      16
#define WS_GATES  (WS_X + B_N * H_N)                  // 32784
#define WS_Q      (WS_GATES + B_N * 4 * H_N)          // 163856
#define WS_KB     (WS_Q + B_N * H_N)                  // 196624
#define WS_EN     (WS_KB + B_N)                       // 196688
#define WS_COMB   (WS_EN + B_N * S_N)                 // 229456
#define WS_SEQE   (WS_COMB + B_N * H_N)               // 262224
#define WS_WSKBF  (WS_SEQE + B_N * S_N)               // 294992 (holds 512*512 ushort, swizzled)
#define WS_LOGITS (WS_WSKBF + (H_N * H_N) / 2)        // 426064
#define WS_COPY   (WS_LOGITS + B_N * V_N)             // 2474064
#define WS_RMAX   (WS_COPY + B_N * VEXT)              // 4525264 (64 uints)
#define WS_RSUM   (WS_RMAX + B_N)                     // +64 floats

__device__ __forceinline__ float sigm(float x) { return 1.0f / (1.0f + expf(-x)); }

__device__ __forceinline__ unsigned short f2bf(float f) {
    unsigned u = __float_as_uint(f);
    u += 0x7fffu + ((u >> 16) & 1u);   // round-to-nearest-even
    return (unsigned short)(u >> 16);
}

// order-preserving float<->uint encode for atomicMax-based scatter-max
__device__ __forceinline__ unsigned enc_f(float f) {
    unsigned u = __float_as_uint(f);
    return (u & 0x80000000u) ? ~u : (u | 0x80000000u);
}
__device__ __forceinline__ float dec_f(unsigned e) {
    unsigned u = (e & 0x80000000u) ? (e & 0x7fffffffu) : ~e;
    return __uint_as_float(u);
}

// ---------- detect bool-mask storage width (1 byte vs 4 byte) ----------
__global__ void kDetect(const unsigned int* __restrict__ m, int* __restrict__ flag) {
    __shared__ int any;
    if (threadIdx.x == 0) any = 0;
    __syncthreads();
    int loc = 0;
    for (int i = threadIdx.x; i < 8192; i += 256) loc |= (m[i] > 1u) ? 1 : 0;
    if (loc) any = 1;
    __syncthreads();
    if (threadIdx.x == 0) *flag = any;   // 1 => byte storage, 0 => int32 storage
}

// ---------- W_seqkey f32 -> bf16, pre-swizzled to MFMA B-fragment order ----------
// layout: swz[((t*16 + kc)*64 + lane)*8 + j] = W[(t*16 + (lane&15))*512 + kc*32 + (lane>>4)*8 + j]
// so a wave's B fragment (n-tile t, k-chunk kc) is one coalesced 1KB global_load_dwordx4.
__global__ void kConvertW(const float* __restrict__ W, unsigned short* __restrict__ swz) {
    const int g = blockIdx.x * 256 + threadIdx.x;      // 32768 threads, 8 elems each
    const int t = g >> 10, kc = (g >> 6) & 15, lane = g & 63;
    const int r = t * 16 + (lane & 15);
    const int k = kc * 32 + (lane >> 4) * 8;
    const float4 v0 = *(const float4*)(W + (size_t)r * 512 + k);
    const float4 v1 = *(const float4*)(W + (size_t)r * 512 + k + 4);
    ushort4 h0, h1;
    h0.x = f2bf(v0.x); h0.y = f2bf(v0.y); h0.z = f2bf(v0.z); h0.w = f2bf(v0.w);
    h1.x = f2bf(v1.x); h1.y = f2bf(v1.y); h1.z = f2bf(v1.z); h1.w = f2bf(v1.w);
    *(ushort4*)(swz + (size_t)g * 8) = h0;
    *(ushort4*)(swz + (size_t)g * 8 + 4) = h1;
}

// ---------- init copy buffer to enc(-INF); block 0 also inits row max/sum ----------
__global__ void kFillCopy(unsigned int* __restrict__ copyenc,
                          unsigned int* __restrict__ rmax, float* __restrict__ rsum) {
    const unsigned NE = enc_f(-INF_F);
    if (blockIdx.x == 0 && threadIdx.x < B_N) {
        rmax[threadIdx.x] = 0u;
        rsum[threadIdx.x] = 0.0f;
    }
    int i0 = (blockIdx.x * 256 + threadIdx.x) * 4;
#pragma unroll
    for (int k = 0; k < 4; k++) {
        int i = i0 + k;
        if (i < B_N * VEXT) copyenc[i] = NE;
    }
}

// ---------- x = [embed[id] | prev_context] @ W_reduce.T + b_reduce ----------
__global__ __launch_bounds__(256) void kEmbedReduce(
        const int* __restrict__ ids, const float* __restrict__ embed,
        const float* __restrict__ pctx, const float* __restrict__ Wred,
        const float* __restrict__ bred, float* __restrict__ x) {
    __shared__ float xc[1024];
    const int tid = threadIdx.x;
    const int b = blockIdx.x >> 1, half = blockIdx.x & 1;
    const float* er = embed + (size_t)ids[b] * 512;
    xc[tid] = er[tid];               xc[tid + 256] = er[tid + 256];
    xc[512 + tid] = pctx[b * 512 + tid]; xc[512 + tid + 256] = pctx[b * 512 + tid + 256];
    __syncthreads();
    const int j = half * 256 + tid;
    const float4* w4 = (const float4*)(Wred + (size_t)j * 1024);
    const float4* x4 = (const float4*)xc;
    float acc = bred[j];
    for (int k = 0; k < 256; k++) {
        float4 w = w4[k], xv = x4[k];
        acc += w.x * xv.x + w.y * xv.y + w.z * xv.z + w.w * xv.w;
    }
    x[b * 512 + j] = acc;
}

// ---------- gates = x @ W_ih.T + h0 @ W_hh.T + b_ih + b_hh ----------
__global__ __launch_bounds__(256) void kGates(
        const float* __restrict__ x, const float* __restrict__ h0,
        const float* __restrict__ Wih, const float* __restrict__ Whh,
        const float* __restrict__ bih, const float* __restrict__ bhh,
        float* __restrict__ gates) {
    __shared__ float xl[512], hl[512];
    const int tid = threadIdx.x;
    const int b = blockIdx.x >> 3, part = blockIdx.x & 7;
    xl[tid] = x[b * 512 + tid];  xl[tid + 256] = x[b * 512 + tid + 256];
    hl[tid] = h0[b * 512 + tid]; hl[tid + 256] = h0[b * 512 + tid + 256];
    __syncthreads();
    const int j = part * 256 + tid;
    const float4* wi4 = (const float4*)(Wih + (size_t)j * 512);
    const float4* wh4 = (const float4*)(Whh + (size_t)j * 512);
    const float4* x4 = (const float4*)xl;
    const float4* h4 = (const float4*)hl;
    float acc = bih[j] + bhh[j];
    for (int k = 0; k < 128; k++) {
        float4 w = wi4[k], xv = x4[k];
        acc += w.x * xv.x + w.y * xv.y + w.z * xv.z + w.w * xv.w;
    }
    for (int k = 0; k < 128; k++) {
        float4 w = wh4[k], hv = h4[k];
        acc += w.x * hv.x + w.y * hv.y + w.z * hv.z + w.w * hv.w;
    }
    gates[(size_t)b * 2048 + j] = acc;
}

// ---------- LSTM elementwise (PyTorch i,f,g,o order) ----------
__global__ __launch_bounds__(256) void kLstm(
        const float* __restrict__ gates, const float* __restrict__ c0,
        float* __restrict__ h1o, float* __restrict__ c1o) {
    const int idx = blockIdx.x * 256 + threadIdx.x;  // < 32768
    const int b = idx >> 9, j = idx & 511;
    const float gi = gates[(size_t)b * 2048 + j];
    const float gf = gates[(size_t)b * 2048 + 512 + j];
    const float gg = gates[(size_t)b * 2048 + 1024 + j];
    const float go = gates[(size_t)b * 2048 + 1536 + j];
    const float cp = c0[idx];
    const float c1 = sigm(gf) * cp + sigm(gi) * tanhf(gg);
    const float h1 = sigm(go) * tanhf(c1);
    h1o[idx] = h1;
    c1o[idx] = c1;
}

// ---------- q[b,k] = sum_h h1[b,h]*W_key[h,k]; kb[b] = b_key . h1[b] ----------
__global__ __launch_bounds__(256) void kQ(
        const float* __restrict__ h1, const float* __restrict__ Wkey,
        const float* __restrict__ bkey, float* __restrict__ q, float* __restrict__ kb) {
    __shared__ float hl[512];
    __shared__ float rd[256];
    const int tid = threadIdx.x;
    const int b = blockIdx.x >> 1, half = blockIdx.x & 1;
    hl[tid] = h1[b * 512 + tid]; hl[tid + 256] = h1[b * 512 + tid + 256];
    __syncthreads();
    const int k = half * 256 + tid;
    float acc = 0.f;
#pragma unroll 4
    for (int h = 0; h < 512; h++) acc += hl[h] * Wkey[(size_t)h * 512 + k];
    q[b * 512 + k] = acc;
    if (half == 0) {   // block-uniform branch
        float p = bkey[tid] * hl[tid] + bkey[tid + 256] * hl[tid + 256];
        rd[tid] = p; __syncthreads();
        for (int st = 128; st > 0; st >>= 1) {
            if (tid < st) rd[tid] += rd[tid + st];
            __syncthreads();
        }
        if (tid == 0) kb[b] = rd[0];
    }
}

// ---------- energies[b,s] = enc[b,s,:].q[b] + kb[b]; mask rows summing to 0 ----------
__global__ __launch_bounds__(256) void kEnergies(
        const float* __restrict__ enc, const float* __restrict__ q,
        const float* __restrict__ kb, float* __restrict__ energ) {
    __shared__ float ql[512];
    __shared__ float pe[256], ps[256];
    const int tid = threadIdx.x;
    const int b = blockIdx.x >> 2;
    const int sc = (blockIdx.x & 3) * 128;
    ql[tid] = q[b * 512 + tid]; ql[tid + 256] = q[b * 512 + tid + 256];
    __syncthreads();
    const int r = tid & 127, hi = tid >> 7;
    const float4* row4 = (const float4*)(enc + (size_t)(b * 512 + sc + r) * 512 + hi * 256);
    const float4* q4 = (const float4*)(ql + hi * 256);
    float e = 0.f, ssum = 0.f;
#pragma unroll 4
    for (int k = 0; k < 64; k++) {
        float4 ev = row4[k], qv = q4[k];
        e += ev.x * qv.x + ev.y * qv.y + ev.z * qv.z + ev.w * qv.w;
        ssum += ev.x + ev.y + ev.z + ev.w;
    }
    pe[tid] = e; ps[tid] = ssum;
    __syncthreads();
    if (tid < 128) {
        float ee = pe[tid] + pe[tid + 128] + kb[b];
        float sm = ps[tid] + ps[tid + 128];
        if (sm == 0.0f) ee = 1e-12f;        // enc_mask semantics
        energ[b * 512 + sc + tid] = ee;
    }
}

// ---------- softmax over S per b ----------
__global__ __launch_bounds__(256) void kSoftmax(
        const float* __restrict__ energ, float* __restrict__ attn) {
    __shared__ float el[512];
    __shared__ float rd[256];
    const int tid = threadIdx.x, b = blockIdx.x;
    el[tid] = energ[b * 512 + tid]; el[tid + 256] = energ[b * 512 + tid + 256];
    __syncthreads();
    rd[tid] = fmaxf(el[tid], el[tid + 256]); __syncthreads();
    for (int st = 128; st > 0; st >>= 1) {
        if (tid < st) rd[tid] = fmaxf(rd[tid], rd[tid + st]);
        __syncthreads();
    }
    const float m = rd[0]; __syncthreads();
    float v0 = expf(el[tid] - m), v1 = expf(el[tid + 256] - m);
    rd[tid] = v0 + v1; __syncthreads();
    for (int st = 128; st > 0; st >>= 1) {
        if (tid < st) rd[tid] += rd[tid + st];
        __syncthreads();
    }
    const float inv = 1.0f / rd[0];
    attn[b * 512 + tid] = v0 * inv;
    attn[b * 512 + tid + 256] = v1 * inv;
}

// ---------- context[b,h] = sum_s attn[b,s]*enc[b,s,h]  (atomicAdd partials) ----------
__global__ __launch_bounds__(256) void kContext(
        const float* __restrict__ enc, const float* __restrict__ attn,
        float* __restrict__ ctx) {
    __shared__ float al[64];
    const int tid = threadIdx.x;
    const int b = blockIdx.x >> 3, sc = (blockIdx.x & 7) * 64;
    if (tid < 64) al[tid] = attn[b * 512 + sc + tid];
    __syncthreads();
    float a0 = 0.f, a1 = 0.f;
    for (int s = 0; s < 64; s++) {
        const float* row = enc + (size_t)(b * 512 + sc + s) * 512;
        const float av = al[s];
        a0 += av * row[tid];
        a1 += av * row[tid + 256];
    }
    atomicAdd(&ctx[b * 512 + tid], a0);
    atomicAdd(&ctx[b * 512 + tid + 256], a1);
}

// ---------- combined = tanh([h1|ctx] @ W_comb.T + b_comb) ----------
__global__ __launch_bounds__(256) void kCombined(
        const float* __restrict__ h1, const float* __restrict__ ctx,
        const float* __restrict__ Wcomb, const float* __restrict__ bcomb,
        float* __restrict__ comb) {
    __shared__ float hc[1024];
    const int tid = threadIdx.x;
    const int b = blockIdx.x >> 1, half = blockIdx.x & 1;
    hc[tid] = h1[b * 512 + tid];        hc[tid + 256] = h1[b * 512 + tid + 256];
    hc[512 + tid] = ctx[b * 512 + tid]; hc[512 + tid + 256] = ctx[b * 512 + tid + 256];
    __syncthreads();
    const int j = half * 256 + tid;
    const float4* w4 = (const float4*)(Wcomb + (size_t)j * 1024);
    const float4* x4 = (const float4*)hc;
    float acc = bcomb[j];
    for (int k = 0; k < 256; k++) {
        float4 w = w4[k], xv = x4[k];
        acc += w.x * xv.x + w.y * xv.y + w.z * xv.z + w.w * xv.w;
    }
    comb[b * 512 + j] = tanhf(acc);
}

// ---------- logits[b,v] = combined[b] . W_out[v] + b_out[v]  (f32, k-split x4) ----------
__global__ __launch_bounds__(256) void kLogits(
        const float* __restrict__ comb, const float* __restrict__ Wout,
        const float* __restrict__ bout, float* __restrict__ logits) {
    __shared__ float cl[4][32][64];   // [kq][kk][b] also reused as reduction scratch
    const int tid = threadIdx.x;
    const int vt = tid & 63, kq = tid >> 6;
    const int v = blockIdx.x * 64 + vt;
    float acc[64];
#pragma unroll
    for (int i = 0; i < 64; i++) acc[i] = 0.f;
    for (int kc = 0; kc < 4; kc++) {
        __syncthreads();
        {
            const float4* s4 = (const float4*)(comb + (size_t)vt * 512 + kq * 128 + kc * 32);
#pragma unroll
            for (int qq = 0; qq < 8; qq++) {
                float4 vv = s4[qq];
                cl[kq][qq * 4 + 0][vt] = vv.x; cl[kq][qq * 4 + 1][vt] = vv.y;
                cl[kq][qq * 4 + 2][vt] = vv.z; cl[kq][qq * 4 + 3][vt] = vv.w;
            }
        }
        __syncthreads();
        float wreg[32];
        const float4* w4 = (const float4*)(Wout + (size_t)v * 512 + kq * 128 + kc * 32);
#pragma unroll
        for (int qq = 0; qq < 8; qq++) {
            float4 wv = w4[qq];
            wreg[qq * 4 + 0] = wv.x; wreg[qq * 4 + 1] = wv.y;
            wreg[qq * 4 + 2] = wv.z; wreg[qq * 4 + 3] = wv.w;
        }
#pragma unroll
        for (int kk = 0; kk < 32; kk++) {
            const float wv = wreg[kk];
            const float4* cp = (const float4*)&cl[kq][kk][0];
#pragma unroll
            for (int b4 = 0; b4 < 16; b4++) {
                float4 c4 = cp[b4];
                acc[b4 * 4 + 0] += wv * c4.x; acc[b4 * 4 + 1] += wv * c4.y;
                acc[b4 * 4 + 2] += wv * c4.z; acc[b4 * 4 + 3] += wv * c4.w;
            }
        }
    }
    float* red = &cl[0][0][0];
    __syncthreads();
    if (kq >= 2) {
#pragma unroll
        for (int b = 0; b < 64; b++) red[(kq - 2) * 4096 + vt * 64 + b] = acc[b];
    }
    __syncthreads();
    if (kq < 2) {
#pragma unroll
        for (int b = 0; b < 64; b++) acc[b] += red[kq * 4096 + vt * 64 + b];
    }
    __syncthreads();
    if (kq == 1) {
#pragma unroll
        for (int b = 0; b < 64; b++) red[vt * 64 + b] = acc[b];
    }
    __syncthreads();
    if (kq == 0) {
        const float bo = bout[v];
#pragma unroll
        for (int b = 0; b < 64; b++)
            logits[(size_t)b * 32000 + v] = acc[b] + red[vt * 64 + b] + bo;
    }
}

// ---------- seq_e[m] = sum_h tanh( (seqs @ W_seqkey.T)[m,h] ) * h1[b,h]  (bf16 MFMA) ----
// Restructured: A (64 rows x 512 K) staged ONCE to LDS as bf16 (stride 520 ushorts,
// conflict-free b128 fragment reads); B read register-direct from pre-swizzled global
// (L2-resident, 1KB coalesced load per wave fragment). No barriers in the K-loop.
#define A_STRIDE 520
__global__ __launch_bounds__(512, 4) void kSeqGemm(
        const float* __restrict__ seqs, const unsigned short* __restrict__ swz,
        const float* __restrict__ h1g, float* __restrict__ seq_e) {
    __shared__ unsigned short a_lds[64 * A_STRIDE];   // 66560 B
    __shared__ float h1l[512];
    __shared__ float partf[8][64];
    const int tid = threadIdx.x;
    const int m0 = blockIdx.x * 64;
    const int b = m0 >> 9;
    const int w = tid >> 6;
    const int lane = tid & 63;
    const int quad = lane >> 4;
    const int c16 = lane & 15;

    h1l[tid] = h1g[b * 512 + tid];

    // ---- stage A once: 64 rows x 512 k f32 -> bf16 in LDS ----
    {
        const int row = tid >> 3, seg = tid & 7;
        const float* src = seqs + (size_t)(m0 + row) * 512 + seg * 4;
        unsigned short* dst = &a_lds[row * A_STRIDE + seg * 4];
#pragma unroll
        for (int i = 0; i < 16; i++) {
            float4 v = *(const float4*)(src + i * 32);
            ushort4 hv;
            hv.x = f2bf(v.x); hv.y = f2bf(v.y); hv.z = f2bf(v.z); hv.w = f2bf(v.w);
            *(ushort4*)(dst + i * 32) = hv;
        }
    }
    __syncthreads();

    floatx4 acc[4][4];
    const floatx4 zf = {0.f, 0.f, 0.f, 0.f};
#pragma unroll
    for (int i = 0; i < 4; i++)
#pragma unroll
        for (int j = 0; j < 4; j++) acc[i][j] = zf;

    // ---- K loop: no barriers; A from LDS, B register-direct from swizzled global ----
    const unsigned short* bbase = swz + (size_t)((w * 4) * 16) * 512 + (size_t)lane * 8;
    // fragment (t = w*4+nt, kc): offset ((t*16 + kc)*64 + lane)*8
#pragma unroll 2
    for (int kc = 0; kc < 16; kc++) {
        bf16x8 af[4], bfr[4];
#pragma unroll
        for (int nt = 0; nt < 4; nt++)
            bfr[nt] = *(const bf16x8*)(bbase + (size_t)(nt * 16 + kc) * 512);
#pragma unroll
        for (int ms = 0; ms < 4; ms++)
            af[ms] = *(const bf16x8*)&a_lds[(ms * 16 + c16) * A_STRIDE + kc * 32 + quad * 8];
#pragma unroll
        for (int ms = 0; ms < 4; ms++)
#pragma unroll
            for (int nt = 0; nt < 4; nt++)
                acc[ms][nt] = __builtin_amdgcn_mfma_f32_16x16x32_bf16(
                    af[ms], bfr[nt], acc[ms][nt], 0, 0, 0);
    }

    // ---- epilogue: seq_e[m] = sum_n tanh(K[m,n]) * h1[b,n] ----
    float psum[16];
#pragma unroll
    for (int i = 0; i < 16; i++) psum[i] = 0.f;
#pragma unroll
    for (int ms = 0; ms < 4; ms++)
#pragma unroll
        for (int nt = 0; nt < 4; nt++) {
            const float hv = h1l[w * 64 + nt * 16 + c16];
#pragma unroll
            for (int r = 0; r < 4; r++)
                psum[ms * 4 + r] += tanhf(acc[ms][nt][r]) * hv;   // D: row=quad*4+r, col=c16
        }
#pragma unroll
    for (int d = 1; d < 16; d <<= 1)
#pragma unroll
        for (int i = 0; i < 16; i++) psum[i] += __shfl_xor(psum[i], d);
    if (c16 == 0) {
#pragma unroll
        for (int ms = 0; ms < 4; ms++)
#pragma unroll
            for (int r = 0; r < 4; r++)
                partf[w][ms * 16 + quad * 4 + r] = psum[ms * 4 + r];
    }
    __syncthreads();
    if (tid < 64) {
        float s = 0.f;
#pragma unroll
        for (int ww = 0; ww < 8; ww++) s += partf[ww][tid];
        seq_e[m0 + tid] = s;
    }
}

// ---------- scatter-max into extended-vocab copy buffer ----------
__global__ __launch_bounds__(512) void kScatter(
        const float* __restrict__ seq_e, const void* __restrict__ mask,
        const int* __restrict__ extix, const int* __restrict__ flag,
        unsigned int* __restrict__ copyenc) {
    const int tid = threadIdx.x, b = blockIdx.x;
    float e = seq_e[b * 512 + tid];
    bool mk;
    if (*flag) mk = ((const unsigned char*)mask)[b * 512 + tid] != 0;
    else       mk = ((const int*)mask)[b * 512 + tid] != 0;
    if (mk) e = 1e-12f;
    const int idx = extix[b * 512 + tid];
    atomicMax(&copyenc[(size_t)b * VEXT + idx], enc_f(e));
}

// ---------- log_softmax stage 1: assemble o, write, atomicMax row max ----------
__global__ __launch_bounds__(256) void kFinal1(
        const float* __restrict__ logits, const unsigned int* __restrict__ copyenc,
        float* __restrict__ out0, unsigned int* __restrict__ rmax) {
    __shared__ float rd[4];
    const int tid = threadIdx.x;
    const int b = blockIdx.x >> 4, chunk = blockIdx.x & 15;
    const int base = chunk * 2048 + tid;
    const float* lrow = logits + (size_t)b * 32000;
    const unsigned int* crow = copyenc + (size_t)b * VEXT;
    float* orow = out0 + (size_t)b * VEXT;
    float lm = -3.0e38f;
#pragma unroll
    for (int k = 0; k < 8; k++) {
        const int j = base + k * 256;
        if (j < VEXT) {
            float ext = (j < 32000) ? lrow[j] : 0.0f;
            float cv = dec_f(crow[j]);
            if (cv == -INF_F) cv = 0.0f;
            float o = ext + cv;
            if (o == 0.0f) o = -INF_F;
            orow[j] = o;
            lm = fmaxf(lm, o);
        }
    }
#pragma unroll
    for (int d = 1; d < 64; d <<= 1) lm = fmaxf(lm, __shfl_xor(lm, d));
    if ((tid & 63) == 0) rd[tid >> 6] = lm;
    __syncthreads();
    if (tid == 0) {
        float m = fmaxf(fmaxf(rd[0], rd[1]), fmaxf(rd[2], rd[3]));
        atomicMax(&rmax[b], enc_f(m));
    }
}

// ---------- log_softmax stage 2: partial exp-sums ----------
__global__ __launch_bounds__(256) void kFinal2(
        const float* __restrict__ out0, const unsigned int* __restrict__ rmax,
        float* __restrict__ rsum) {
    __shared__ float rd[4];
    const int tid = threadIdx.x;
    const int b = blockIdx.x >> 4, chunk = blockIdx.x & 15;
    const int base = chunk * 2048 + tid;
    const float* orow = out0 + (size_t)b * VEXT;
    const float m = dec_f(rmax[b]);
    float s = 0.f;
#pragma unroll
    for (int k = 0; k < 8; k++) {
        const int j = base + k * 256;
        if (j < VEXT) s += expf(orow[j] - m);
    }
#pragma unroll
    for (int d = 1; d < 64; d <<= 1) s += __shfl_xor(s, d);
    if ((tid & 63) == 0) rd[tid >> 6] = s;
    __syncthreads();
    if (tid == 0) atomicAdd(&rsum[b], rd[0] + rd[1] + rd[2] + rd[3]);
}

// ---------- log_softmax stage 3: subtract lse ----------
__global__ __launch_bounds__(256) void kFinal3(
        float* __restrict__ out0, const unsigned int* __restrict__ rmax,
        const float* __restrict__ rsum) {
    const int tid = threadIdx.x;
    const int b = blockIdx.x >> 4, chunk = blockIdx.x & 15;
    const int base = chunk * 2048 + tid;
    float* orow = out0 + (size_t)b * VEXT;
    const float lse = dec_f(rmax[b]) + logf(rsum[b]);
#pragma unroll
    for (int k = 0; k < 8; k++) {
        const int j = base + k * 256;
        if (j < VEXT) orow[j] -= lse;
    }
}

extern "C" void kernel_launch(void* const* d_in, const int* in_sizes, int n_in,
                              void* d_out, int out_size, void* d_ws, size_t ws_size,
                              hipStream_t stream) {
    const int*   ids   = (const int*)d_in[0];
    const float* pctx  = (const float*)d_in[1];
    const float* h0    = (const float*)d_in[2];
    const float* c0    = (const float*)d_in[3];
    const float* enc   = (const float*)d_in[4];
    const float* seqs  = (const float*)d_in[5];
    const void*  mask  = d_in[6];
    const int*   extix = (const int*)d_in[7];
    const float* embed = (const float*)d_in[8];
    const float* Wred  = (const float*)d_in[9];
    const float* bred  = (const float*)d_in[10];
    const float* Wkey  = (const float*)d_in[11];
    const float* bkey  = (const float*)d_in[12];
    const float* Wcomb = (const float*)d_in[13];
    const float* bcomb = (const float*)d_in[14];
    const float* Wseqk = (const float*)d_in[15];
    const float* Wih   = (const float*)d_in[16];
    const float* Whh   = (const float*)d_in[17];
    const float* bih   = (const float*)d_in[18];
    const float* bhh   = (const float*)d_in[19];
    const float* Wout  = (const float*)d_in[20];
    const float* bout  = (const float*)d_in[21];
    (void)in_sizes; (void)n_in; (void)out_size; (void)ws_size;

    float* out = (float*)d_out;
    float* ws = (float*)d_ws;
    int* flag = (int*)ws;
    float* xws = ws + WS_X;
    float* gatesws = ws + WS_GATES;
    float* qws = ws + WS_Q;
    float* kbws = ws + WS_KB;
    float* enws = ws + WS_EN;
    float* combws = ws + WS_COMB;
    float* seqews = ws + WS_SEQE;
    unsigned short* wsk = (unsigned short*)(ws + WS_WSKBF);
    float* logitsws = ws + WS_LOGITS;
    unsigned int* copyenc = (unsigned int*)(ws + WS_COPY);
    unsigned int* rmax = (unsigned int*)(ws + WS_RMAX);
    float* rsum = ws + WS_RSUM;

    kDetect<<<1, 256, 0, stream>>>((const unsigned int*)mask, flag);
    kConvertW<<<128, 256, 0, stream>>>(Wseqk, wsk);
    kFillCopy<<<2004, 256, 0, stream>>>(copyenc, rmax, rsum);
    kEmbedReduce<<<128, 256, 0, stream>>>(ids, embed, pctx, Wred, bred, xws);
    kGates<<<512, 256, 0, stream>>>(xws, h0, Wih, Whh, bih, bhh, gatesws);
    kLstm<<<128, 256, 0, stream>>>(gatesws, c0, out + OFF_H1, out + OFF_C1);
    kQ<<<128, 256, 0, stream>>>(out + OFF_H1, Wkey, bkey, qws, kbws);
    kEnergies<<<256, 256, 0, stream>>>(enc, qws, kbws, enws);
    kSoftmax<<<64, 256, 0, stream>>>(enws, out + OFF_ATTN);
    hipMemsetAsync(out + OFF_CTX, 0, (size_t)B_N * H_N * sizeof(float), stream);
    kContext<<<512, 256, 0, stream>>>(enc, out + OFF_ATTN, out + OFF_CTX);
    kCombined<<<128, 256, 0, stream>>>(out + OFF_H1, out + OFF_CTX, Wcomb, bcomb, combws);
    kLogits<<<500, 256, 0, stream>>>(combws, Wout, bout, logitsws);
    kSeqGemm<<<512, 512, 0, stream>>>(seqs, wsk, out + OFF_H1, seqews);
    kScatter<<<64, 512, 0, stream>>>(seqews, mask, extix, flag, copyenc);
    kFinal1<<<1024, 256, 0, stream>>>(logitsws, copyenc, out + OFF_OUT0, rmax);
    kFinal2<<<1024, 256, 0, stream>>>(out + OFF_OUT0, rmax, rsum);
    kFinal3<<<1024, 256, 0, stream>>>(out + OFF_OUT0, rmax, rsum);
}